// Round 3
// baseline (178.349 us; speedup 1.0000x reference)
//
#include <hip/hip_runtime.h>
#include <hip/hip_bf16.h>
#include <math.h>

// HyenaFilter2D: out = u*D + 9-tap shifted conv (see derivation in earlier rounds).
// The Gaussian modulation exp(-0.5*(r^2/delta)^2), delta in [0.1,0.3], kills every
// kernel tap except the 3x3 neighborhood of (256,256); the double FFT normalization
// scales the conv by 1/2^20. Valid shifted reads require out row i>=255 and col
// j>=255 (bottom-right quadrant), reading u rows/cols [0,256].
//
// Fused single kernel: each block owns 16 contiguous rows of one (b,c) image.
// Blocks intersecting the conv quadrant cooperatively recompute the 9-position
// sin-MLP (redundantly per block; ~115K FMA amortized over 256 threads) and apply
// the conv with L1-resident coalesced window loads.

#define HDIM 512
#define WDIM 512
#define CDIM 32
#define BDIM 2
#define HW   (HDIM*WDIM)
#define TOTAL4 (BDIM*CDIM*HW/4)   // 4,194,304 float4 groups
#define NBLOCK 2048               // 32 blocks per (b,c) image, 16 rows each
#define CHUNK4 (TOTAL4/NBLOCK)    // 2048 float4 per block

__global__ __launch_bounds__(256) void hyena_fused_kernel(
    const float* __restrict__ u,      // [B, C, 512, 512]
    const float* __restrict__ zh,     // [512, 5]
    const float* __restrict__ zw,     // [512, 5]
    const float* __restrict__ W0,     // [10, 64]
    const float* __restrict__ b0,     // [64]
    const float* __restrict__ W1,     // [64, 64]
    const float* __restrict__ b1,     // [64]
    const float* __restrict__ W2,     // [64, 64]
    const float* __restrict__ b2,     // [64]
    const float* __restrict__ Wout,   // [64, 32]
    const float* __restrict__ freq,   // [64]
    const float* __restrict__ deltas, // [32]
    const float* __restrict__ D,      // [32]
    float* __restrict__ out)          // [B, C, 512, 512]
{
    __shared__ float HA[576];   // [9 positions][64 hidden]
    __shared__ float HB[576];
    __shared__ float tps[9];

    const int block = blockIdx.x;
    const int bc  = block >> 5;        // 0..63  (b*32 + c)
    const int c   = bc & 31;
    const int sub = block & 31;        // rows [sub*16, sub*16+16)
    const int t   = threadIdx.x;

    const bool need_taps = (sub >= 15);   // rows >= 240 can include row >= 255

    if (need_taps) {
        // ---- layer 0: 10 -> 64, for all 9 positions (576 units over 256 threads)
        for (int n = t; n < 576; n += 256) {
            int p = n >> 6, o = n & 63;
            int di = p / 3 - 1, dj = p % 3 - 1;
            float acc = b0[o];
            #pragma unroll
            for (int e = 0; e < 5; e++) acc += zh[(256 + di) * 5 + e] * W0[e * 64 + o];
            #pragma unroll
            for (int e = 0; e < 5; e++) acc += zw[(256 + dj) * 5 + e] * W0[(5 + e) * 64 + o];
            HA[n] = sinf(freq[o] * acc);
        }
        __syncthreads();
        // ---- layer 1: 64 -> 64
        for (int n = t; n < 576; n += 256) {
            int p = n >> 6, o = n & 63;
            float acc = b1[o];
            #pragma unroll 8
            for (int e = 0; e < 64; e++) acc += HA[(p << 6) + e] * W1[e * 64 + o];
            HB[n] = sinf(freq[o] * acc);
        }
        __syncthreads();
        // ---- layer 2: 64 -> 64
        for (int n = t; n < 576; n += 256) {
            int p = n >> 6, o = n & 63;
            float acc = b2[o];
            #pragma unroll 8
            for (int e = 0; e < 64; e++) acc += HB[(p << 6) + e] * W2[e * 64 + o];
            HA[n] = sinf(freq[o] * acc);
        }
        __syncthreads();
        // ---- output layer: 64 -> 1 (this block's channel only), x9 positions
        if (t < 9) {
            int p = t;
            int di = p / 3 - 1, dj = p % 3 - 1;
            float acc = 0.0f;
            #pragma unroll 8
            for (int e = 0; e < 64; e++) acc += HA[(p << 6) + e] * Wout[e * 32 + c];
            float delta = deltas[c];
            float r2 = (float)(di * di + dj * dj);
            float q = r2 / delta;
            float scaler = expf(-0.5f * q * q) / (delta * 2.5066282746310002f);
            tps[p] = acc * scaler * (1.0f / (1024.0f * 1024.0f));
        }
        __syncthreads();
    }

    float tp[3][3];
    if (need_taps) {
        #pragma unroll
        for (int a = 0; a < 3; a++)
            #pragma unroll
            for (int bb = 0; bb < 3; bb++)
                tp[a][bb] = tps[a * 3 + bb];
    }

    const float d = D[c];
    const float* ubase = u + bc * HW;
    const int base4 = block * CHUNK4;

    for (int k = 0; k < 8; k++) {
        int idx4 = base4 + t + k * 256;
        int idx  = idx4 << 2;
        int rem  = idx & (HW - 1);
        int i    = rem >> 9;        // row within image
        int j0   = rem & 511;       // col (multiple of 4)

        const float4 uv = *reinterpret_cast<const float4*>(u + idx);
        float o0 = uv.x * d, o1 = uv.y * d, o2 = uv.z * d, o3 = uv.w * d;

        if (need_taps && i >= 255 && j0 >= 252) {
            #pragma unroll
            for (int a = 0; a < 3; a++) {
                int si = i - 255 - a;           // shifted source row, 0..256
                if (si < 0) continue;
                const float* row = ubase + si * WDIM;
                float w[6];
                // w[m] = row[j0-257+m]; cols j0-257..j0-252, guarded below 0
                w[0] = (j0 >= 260) ? row[j0 - 257] : 0.0f;
                if (j0 >= 256) {
                    const float4 Bv = *reinterpret_cast<const float4*>(row + j0 - 256);
                    w[1] = Bv.x; w[2] = Bv.y; w[3] = Bv.z; w[4] = Bv.w;
                } else {
                    w[1] = w[2] = w[3] = w[4] = 0.0f;
                }
                w[5] = row[j0 - 252];           // j0-252 >= 0 always here
                #pragma unroll
                for (int bb = 0; bb < 3; bb++) {
                    float tv = tp[a][bb];
                    o0 += tv * w[2 - bb + 0];
                    o1 += tv * w[2 - bb + 1];
                    o2 += tv * w[2 - bb + 2];
                    o3 += tv * w[2 - bb + 3];
                }
            }
        }

        *reinterpret_cast<float4*>(out + idx) = make_float4(o0, o1, o2, o3);
    }
}

extern "C" void kernel_launch(void* const* d_in, const int* in_sizes, int n_in,
                              void* d_out, int out_size, void* d_ws, size_t ws_size,
                              hipStream_t stream) {
    const float* u      = (const float*)d_in[0];
    const float* zh     = (const float*)d_in[1];
    const float* zw     = (const float*)d_in[2];
    const float* W0     = (const float*)d_in[3];
    const float* b0     = (const float*)d_in[4];
    const float* W1     = (const float*)d_in[5];
    const float* b1     = (const float*)d_in[6];
    const float* W2     = (const float*)d_in[7];
    const float* b2     = (const float*)d_in[8];
    const float* Wout   = (const float*)d_in[9];
    const float* freq   = (const float*)d_in[10];
    const float* deltas = (const float*)d_in[11];
    const float* D      = (const float*)d_in[12];
    float* out = (float*)d_out;

    hyena_fused_kernel<<<NBLOCK, 256, 0, stream>>>(u, zh, zw, W0, b0, W1, b1,
                                                   W2, b2, Wout, freq, deltas,
                                                   D, out);
}

// Round 5
// 149.197 us; speedup vs baseline: 1.1954x; 1.1954x over previous
//
#include <hip/hip_runtime.h>
#include <hip/hip_bf16.h>
#include <math.h>

// HyenaFilter2D: out = u*D + 9-tap shifted conv (see derivation in earlier rounds).
// Gaussian modulation exp(-0.5*(r^2/delta)^2), delta in [0.1,0.3], kills all kernel
// taps except the 3x3 neighborhood of (256,256); double FFT normalization scales the
// conv by 1/2^20. Valid shifted reads require out row i>=255 AND col j>=255
// (bottom-right quadrant), reading u rows/cols [0,256].
//
// Structure: tiny taps kernel (9 blocks) + streaming kernel where each thread
// PRELOADS 8 independent float4s (8 outstanding VMEM/wave for latency hiding),
// then applies the conv fixup only on quadrant waves.

#define HDIM 512
#define WDIM 512
#define CDIM 32
#define BDIM 2
#define HW   (HDIM*WDIM)
#define TOTAL4 (BDIM*CDIM*HW/4)   // 4,194,304 float4 groups
#define NBLOCK 2048               // 32 blocks per (b,c) image, 16 rows each
#define CHUNK4 2048               // float4 groups per block

// ---------------- tap computation: 9 blocks (positions) x 64 lanes (hidden units) ----
__global__ __launch_bounds__(64) void compute_taps_kernel(
    const float* __restrict__ zh,   // [512, 5]
    const float* __restrict__ zw,   // [512, 5]
    const float* __restrict__ W0,   // [10, 64]
    const float* __restrict__ b0,   // [64]
    const float* __restrict__ W1,   // [64, 64]
    const float* __restrict__ b1,   // [64]
    const float* __restrict__ W2,   // [64, 64]
    const float* __restrict__ b2,   // [64]
    const float* __restrict__ Wout, // [64, 32]
    const float* __restrict__ freq, // [64]
    const float* __restrict__ deltas, // [32]
    float* __restrict__ taps)       // [9][32] in ws
{
    int p = blockIdx.x;      // 0..8 tap position
    int o = threadIdx.x;     // 0..63 hidden unit
    int di = p / 3 - 1;
    int dj = p % 3 - 1;
    int i = 256 + di;
    int j = 256 + dj;

    __shared__ float sh[64];

    float z[10];
    #pragma unroll
    for (int e = 0; e < 5; e++) z[e]     = zh[i * 5 + e];
    #pragma unroll
    for (int e = 0; e < 5; e++) z[5 + e] = zw[j * 5 + e];

    float f = freq[o];

    float acc = b0[o];
    #pragma unroll
    for (int e = 0; e < 10; e++) acc += z[e] * W0[e * 64 + o];
    float h = sinf(f * acc);
    sh[o] = h;
    __syncthreads();

    acc = b1[o];
    #pragma unroll 8
    for (int e = 0; e < 64; e++) acc += sh[e] * W1[e * 64 + o];
    h = sinf(f * acc);
    __syncthreads();
    sh[o] = h;
    __syncthreads();

    acc = b2[o];
    #pragma unroll 8
    for (int e = 0; e < 64; e++) acc += sh[e] * W2[e * 64 + o];
    h = sinf(f * acc);
    __syncthreads();
    sh[o] = h;
    __syncthreads();

    if (o < 32) {
        float ho = 0.0f;
        #pragma unroll 8
        for (int e = 0; e < 64; e++) ho += sh[e] * Wout[e * 32 + o];
        float delta = deltas[o];
        float r2 = (float)(di * di + dj * dj);
        float q = r2 / delta;
        float scaler = expf(-0.5f * q * q) / (delta * 2.5066282746310002f);
        taps[p * 32 + o] = ho * scaler * (1.0f / (1024.0f * 1024.0f));
    }
}

// ---------------- streaming elementwise + quadrant conv fixup ----------------
__global__ __launch_bounds__(256) void hyena_main_kernel(
    const float* __restrict__ u,    // [B, C, 512, 512]
    const float* __restrict__ D,    // [32]
    const float* __restrict__ taps, // [9][32]
    float* __restrict__ out)        // [B, C, 512, 512]
{
    const int block = blockIdx.x;
    const int bc  = block >> 5;        // b*32 + c
    const int c   = bc & 31;
    const int sub = block & 31;        // rows [sub*16, sub*16+16)
    const int t   = threadIdx.x;

    const int g0  = (block << 11) + t;           // first float4 group of this thread
    const float* __restrict__ up = u + (g0 << 2);

    // ---- branch-free preload: 8 independent float4 loads in flight ----
    float4 v[8];
    #pragma unroll
    for (int k = 0; k < 8; ++k)
        v[k] = *reinterpret_cast<const float4*>(up + (k << 10));  // +1024 floats = 2 rows

    const float d = D[c];
    #pragma unroll
    for (int k = 0; k < 8; ++k) {
        v[k].x *= d; v[k].y *= d; v[k].z *= d; v[k].w *= d;
    }

    // ---- conv fixup: only quadrant (row>=255, out col>=255) ----
    // col of this thread's groups: j0 = (t&127)*4, identical across k.
    const int j0     = (t & 127) << 2;
    const int i_base = (sub << 4) + (t >> 7);    // row of k=0 group
    if (sub >= 15 && j0 >= 252) {
        float tp[9];
        #pragma unroll
        for (int p = 0; p < 9; ++p) tp[p] = taps[p * 32 + c];   // block-uniform

        const float* __restrict__ ubase = u + bc * HW;
        #pragma unroll
        for (int k = 0; k < 8; ++k) {
            int i = i_base + (k << 1);
            if (i < 255) continue;
            #pragma unroll
            for (int a = 0; a < 3; ++a) {
                int si = i - 255 - a;            // source row, 0..256
                if (si < 0) continue;
                const float* row = ubase + si * WDIM;
                float w[6];                      // w[m] = row[j0-257+m]
                w[0] = (j0 >= 260) ? row[j0 - 257] : 0.0f;
                if (j0 >= 256) {
                    const float4 Bv = *reinterpret_cast<const float4*>(row + j0 - 256);
                    w[1] = Bv.x; w[2] = Bv.y; w[3] = Bv.z; w[4] = Bv.w;
                } else {
                    w[1] = w[2] = w[3] = w[4] = 0.0f;
                }
                w[5] = row[j0 - 252];
                #pragma unroll
                for (int bb = 0; bb < 3; ++bb) {
                    float tv = tp[a * 3 + bb];
                    v[k].x += tv * w[2 - bb + 0];
                    v[k].y += tv * w[2 - bb + 1];
                    v[k].z += tv * w[2 - bb + 2];
                    v[k].w += tv * w[2 - bb + 3];
                }
            }
        }
    }

    // ---- stores ----
    float* __restrict__ op = out + (g0 << 2);
    #pragma unroll
    for (int k = 0; k < 8; ++k)
        *reinterpret_cast<float4*>(op + (k << 10)) = v[k];
}

extern "C" void kernel_launch(void* const* d_in, const int* in_sizes, int n_in,
                              void* d_out, int out_size, void* d_ws, size_t ws_size,
                              hipStream_t stream) {
    const float* u      = (const float*)d_in[0];
    const float* zh     = (const float*)d_in[1];
    const float* zw     = (const float*)d_in[2];
    const float* W0     = (const float*)d_in[3];
    const float* b0     = (const float*)d_in[4];
    const float* W1     = (const float*)d_in[5];
    const float* b1     = (const float*)d_in[6];
    const float* W2     = (const float*)d_in[7];
    const float* b2     = (const float*)d_in[8];
    const float* Wout   = (const float*)d_in[9];
    const float* freq   = (const float*)d_in[10];
    const float* deltas = (const float*)d_in[11];
    const float* D      = (const float*)d_in[12];
    float* out  = (float*)d_out;
    float* taps = (float*)d_ws;   // 9*32 floats

    compute_taps_kernel<<<9, 64, 0, stream>>>(zh, zw, W0, b0, W1, b1, W2, b2,
                                              Wout, freq, deltas, taps);
    hyena_main_kernel<<<NBLOCK, 256, 0, stream>>>(u, D, taps, out);
}